// Round 1
// baseline (743.987 us; speedup 1.0000x reference)
//
#include <hip/hip_runtime.h>
#include <hip/hip_bf16.h>

typedef __bf16 bf16x8 __attribute__((ext_vector_type(8)));
typedef float  f32x4  __attribute__((ext_vector_type(4)));

// ---------- helpers ----------
static __device__ __forceinline__ unsigned short f2bf(float f) {
  unsigned int u = __float_as_uint(f);
  u += 0x7FFFu + ((u >> 16) & 1u);   // round-to-nearest-even
  return (unsigned short)(u >> 16);
}

static __device__ __forceinline__ void gl_lds16(const void* g, void* l) {
  __builtin_amdgcn_global_load_lds(
      (const __attribute__((address_space(1))) void*)g,
      (__attribute__((address_space(3))) void*)l,
      16, 0, 0);
}

// ---------- cast x: f32 -> bf16 ----------
__global__ __launch_bounds__(256) void cast_f32_bf16(
    const float* __restrict__ in, unsigned short* __restrict__ out, int n) {
  int i = (blockIdx.x * 256 + threadIdx.x) * 4;
  const int stride = gridDim.x * 256 * 4;
  for (; i < n; i += stride) {
    float4 f = *(const float4*)(in + i);
    ushort4 o;
    o.x = f2bf(f.x); o.y = f2bf(f.y); o.z = f2bf(f.z); o.w = f2bf(f.w);
    *(ushort4*)(out + i) = o;
  }
}

// ---------- transpose-cast W (1024x1024): wt[n][k] = w[k][n], f32 -> bf16 ----------
__global__ __launch_bounds__(256) void transpose_cast_w(
    const float* __restrict__ w, unsigned short* __restrict__ wt) {
  __shared__ float tile[16][17];
  const int tx = threadIdx.x & 15, ty = threadIdx.x >> 4;
  const int bx = blockIdx.x * 16, by = blockIdx.y * 16;
  tile[ty][tx] = w[(size_t)(by + ty) * 1024 + bx + tx];
  __syncthreads();
  wt[(size_t)(bx + ty) * 1024 + by + tx] = f2bf(tile[tx][ty]);
}

// ---------- 128x128-tile bf16 MFMA GEMM, B given transposed ([N][K]) ----------
// MODE 0: C bf16 [row*ldc+col]
// MODE 1: C = v written transposed per batch: vt[(b*1024+col)*2048 + s], b=row>>11, s=row&2047
// MODE 2: C f32 [row*ldc+col]
template <int MODE>
__global__ __launch_bounds__(256, 2) void gemm_bt(
    const unsigned short* __restrict__ A, int lda,
    const unsigned short* __restrict__ B, int ldb,
    int K, void* __restrict__ Cv, int ldc) {
  __shared__ __align__(16) unsigned char lds[16384];  // A tile 8KB | B tile 8KB
  const int bn0 = blockIdx.x * 128;
  const int bm0 = blockIdx.y * 128;
  const int tid = threadIdx.x;
  const int wid = tid >> 6, lane = tid & 63;
  const int wr = wid >> 1, wc = wid & 1;
  const int l15 = lane & 15, kq = lane >> 4;

  // staging source mapping: element e = i*2048 + wid*512 + lane*8 -> (row e>>5, col e&31)
  const int e0 = wid * 512 + lane * 8;
  const int r0 = e0 >> 5, c0 = e0 & 31;
  const size_t aoff0 = (size_t)(bm0 + r0) * lda + c0;
  const size_t aoff1 = (size_t)(bm0 + r0 + 64) * lda + c0;
  const size_t boff0 = (size_t)(bn0 + r0) * ldb + c0;
  const size_t boff1 = (size_t)(bn0 + r0 + 64) * ldb + c0;
  unsigned char* ldsA = lds + wid * 1024;         // wave-uniform base
  unsigned char* ldsB = lds + 8192 + wid * 1024;

  f32x4 acc[4][4] = {};
  const int nkt = K >> 5;
  for (int kt = 0; kt < nkt; ++kt) {
    const int kc = kt << 5;
    gl_lds16(A + aoff0 + kc, ldsA);
    gl_lds16(A + aoff1 + kc, ldsA + 4096);
    gl_lds16(B + boff0 + kc, ldsB);
    gl_lds16(B + boff1 + kc, ldsB + 4096);
    __syncthreads();   // compiler drains vmcnt before s_barrier

    bf16x8 af[4], bg[4];
#pragma unroll
    for (int mi = 0; mi < 4; ++mi)
      af[mi] = *(const bf16x8*)(lds + ((wr * 64 + mi * 16 + l15) * 64 + kq * 16));
#pragma unroll
    for (int ni = 0; ni < 4; ++ni)
      bg[ni] = *(const bf16x8*)(lds + 8192 + ((wc * 64 + ni * 16 + l15) * 64 + kq * 16));
#pragma unroll
    for (int mi = 0; mi < 4; ++mi)
#pragma unroll
      for (int ni = 0; ni < 4; ++ni)
        acc[mi][ni] = __builtin_amdgcn_mfma_f32_16x16x32_bf16(af[mi], bg[ni], acc[mi][ni], 0, 0, 0);
    __syncthreads();
  }

  // epilogue: C/D layout col = lane&15, row = (lane>>4)*4 + reg  [verified m89/m91]
#pragma unroll
  for (int mi = 0; mi < 4; ++mi) {
#pragma unroll
    for (int ni = 0; ni < 4; ++ni) {
#pragma unroll
      for (int r = 0; r < 4; ++r) {
        const int row = bm0 + wr * 64 + mi * 16 + kq * 4 + r;
        const int col = bn0 + wc * 64 + ni * 16 + l15;
        const float v = acc[mi][ni][r];
        if constexpr (MODE == 0) {
          ((unsigned short*)Cv)[(size_t)row * ldc + col] = f2bf(v);
        } else if constexpr (MODE == 1) {
          const int b = row >> 11, s = row & 2047;
          ((unsigned short*)Cv)[((size_t)(b * 1024 + col)) * 2048 + s] = f2bf(v);
        } else {
          ((float*)Cv)[(size_t)row * ldc + col] = v;
        }
      }
    }
  }
}

// ---------- row softmax over 2048 fp32 scores; writes bf16 P in-place (ld 4096) ----------
__global__ __launch_bounds__(256) void softmax_rows(float* __restrict__ scores) {
  const int row = blockIdx.x;
  float* base = scores + (size_t)row * 2048;
  const int tid = threadIdx.x;
  const int wid = tid >> 6, lane = tid & 63;

  float v[8];
  float m = -1e30f;
#pragma unroll
  for (int i = 0; i < 8; ++i) {
    v[i] = base[tid + i * 256] * 0.03125f;  // 1/sqrt(1024)
    m = fmaxf(m, v[i]);
  }
  for (int off = 32; off; off >>= 1) m = fmaxf(m, __shfl_xor(m, off));
  __shared__ float redm[4], reds[4];
  if (lane == 0) redm[wid] = m;
  __syncthreads();            // all global reads of this row complete before here
  m = fmaxf(fmaxf(redm[0], redm[1]), fmaxf(redm[2], redm[3]));

  float s = 0.f;
#pragma unroll
  for (int i = 0; i < 8; ++i) { v[i] = expf(v[i] - m); s += v[i]; }
  for (int off = 32; off; off >>= 1) s += __shfl_xor(s, off);
  if (lane == 0) reds[wid] = s;
  __syncthreads();
  s = reds[0] + reds[1] + reds[2] + reds[3];
  const float inv = 1.0f / s;

  unsigned short* p = (unsigned short*)base;  // bf16 P, ld 4096, in-place (safe: writes after barrier)
#pragma unroll
  for (int i = 0; i < 8; ++i) p[tid + i * 256] = f2bf(v[i] * inv);
}

// ---------- launch ----------
extern "C" void kernel_launch(void* const* d_in, const int* in_sizes, int n_in,
                              void* d_out, int out_size, void* d_ws, size_t ws_size,
                              hipStream_t stream) {
  const float* x  = (const float*)d_in[0];
  const float* Wq = (const float*)d_in[1];
  const float* Wk = (const float*)d_in[2];
  const float* Wv = (const float*)d_in[3];
  float* out = (float*)d_out;
  char* ws = (char*)d_ws;

  // workspace layout (bytes)
  unsigned short* xb  = (unsigned short*)ws;                    // 33.5 MB (reused as scores later)
  unsigned short* wtq = (unsigned short*)(ws + 33554432);       // 2 MB
  unsigned short* wtk = wtq + 1048576;                          // 2 MB
  unsigned short* wtv = wtk + 1048576;                          // 2 MB
  unsigned short* qb  = (unsigned short*)(ws + 39845888);       // 33.5 MB
  unsigned short* kb  = (unsigned short*)(ws + 73400320);       // 33.5 MB
  unsigned short* vt  = (unsigned short*)(ws + 106954752);      // 33.5 MB  (end ~140.5 MB)
  float* scores = (float*)ws;                                   // per-batch 16.8 MB, reuses xb

  cast_f32_bf16<<<2048, 256, 0, stream>>>(x, xb, 16384 * 1024);
  transpose_cast_w<<<dim3(64, 64), 256, 0, stream>>>(Wq, wtq);
  transpose_cast_w<<<dim3(64, 64), 256, 0, stream>>>(Wk, wtk);
  transpose_cast_w<<<dim3(64, 64), 256, 0, stream>>>(Wv, wtv);

  // QKV projections: M=16384, N=1024, K=1024
  gemm_bt<0><<<dim3(8, 128), 256, 0, stream>>>(xb, 1024, wtq, 1024, 1024, qb, 1024);
  gemm_bt<0><<<dim3(8, 128), 256, 0, stream>>>(xb, 1024, wtk, 1024, 1024, kb, 1024);
  gemm_bt<1><<<dim3(8, 128), 256, 0, stream>>>(xb, 1024, wtv, 1024, 1024, vt, 0);

  for (int b = 0; b < 8; ++b) {
    const size_t so = (size_t)b * 2048 * 1024;
    // scores = q·k^T (fp32): M=N=2048, K=1024
    gemm_bt<2><<<dim3(16, 16), 256, 0, stream>>>(qb + so, 1024, kb + so, 1024, 1024, scores, 2048);
    // softmax rows (applies 1/32 scale), P bf16 in-place at ld 4096
    softmax_rows<<<2048, 256, 0, stream>>>(scores);
    // out = P·v : A=P (lda 4096), B^T = vT_b [1024][2048], M=2048, N=1024, K=2048
    gemm_bt<2><<<dim3(8, 16), 256, 0, stream>>>((const unsigned short*)scores, 4096,
                                                vt + (size_t)b * 1024 * 2048, 2048,
                                                2048, out + so, 1024);
  }
}

// Round 2
// 439.188 us; speedup vs baseline: 1.6940x; 1.6940x over previous
//
#include <hip/hip_runtime.h>
#include <hip/hip_bf16.h>

typedef __bf16 bf16x8 __attribute__((ext_vector_type(8)));
typedef float  f32x4  __attribute__((ext_vector_type(4)));

// ---------- helpers ----------
static __device__ __forceinline__ unsigned short f2bf(float f) {
  unsigned int u = __float_as_uint(f);
  u += 0x7FFFu + ((u >> 16) & 1u);   // round-to-nearest-even
  return (unsigned short)(u >> 16);
}

static __device__ __forceinline__ void gl_lds16(const void* g, void* l) {
  __builtin_amdgcn_global_load_lds(
      (const __attribute__((address_space(1))) void*)g,
      (__attribute__((address_space(3))) void*)l,
      16, 0, 0);
}

// ---------- cast x: f32 -> bf16 ----------
__global__ __launch_bounds__(256) void cast_f32_bf16(
    const float* __restrict__ in, unsigned short* __restrict__ out, int n) {
  int i = (blockIdx.x * 256 + threadIdx.x) * 4;
  const int stride = gridDim.x * 256 * 4;
  for (; i < n; i += stride) {
    float4 f = *(const float4*)(in + i);
    ushort4 o;
    o.x = f2bf(f.x); o.y = f2bf(f.y); o.z = f2bf(f.z); o.w = f2bf(f.w);
    *(ushort4*)(out + i) = o;
  }
}

// ---------- transpose-cast W (1024x1024): wt[n][k] = w[k][n], f32 -> bf16 ----------
__global__ __launch_bounds__(256) void transpose_cast_w(
    const float* __restrict__ w, unsigned short* __restrict__ wt) {
  __shared__ float tile[16][17];
  const int tx = threadIdx.x & 15, ty = threadIdx.x >> 4;
  const int bx = blockIdx.x * 16, by = blockIdx.y * 16;
  tile[ty][tx] = w[(size_t)(by + ty) * 1024 + bx + tx];
  __syncthreads();
  wt[(size_t)(bx + ty) * 1024 + by + tx] = f2bf(tile[tx][ty]);
}

// ---------- 128x128-tile bf16 MFMA GEMM, B given transposed ([N][K]) ----------
// Tile rasterization is remapped so tiles sharing an A row-panel land on the
// same XCD (slot d -> tile (d/gy, d%gy); requires gridDim.y % 8 == 0).
// blockIdx.z selects the batch: A += z*astride, B += z*bstride, C += z*cstride.
// MODE 2: C f32 at [row*ldc+col]
// MODE 3: fused-QKV split write: Cv = qb base; kb = qb+16Mi, vt = kb+16Mi;
//         col<1024 -> q bf16 [row][col]; col<2048 -> k bf16 [row][col-1024];
//         col>=2048 -> vT bf16 [(b*1024+col-2048)][s], b=row>>11, s=row&2047
template <int MODE>
__global__ __launch_bounds__(256, 2) void gemm_bt(
    const unsigned short* __restrict__ A, int lda, size_t astride,
    const unsigned short* __restrict__ B, int ldb, size_t bstride,
    int K, void* __restrict__ Cv, int ldc, size_t cstride) {
  __shared__ __align__(16) unsigned char lds[16384];  // A tile 8KB | B tile 8KB
  // ----- XCD-locality rasterization remap -----
  const unsigned d2 = blockIdx.x + gridDim.x * blockIdx.y;
  const unsigned ty = d2 % gridDim.y;
  const unsigned tx = d2 / gridDim.y;
  const int bn0 = tx * 128;
  const int bm0 = ty * 128;

  A += (size_t)blockIdx.z * astride;
  B += (size_t)blockIdx.z * bstride;

  const int tid = threadIdx.x;
  const int wid = tid >> 6, lane = tid & 63;
  const int wr = wid >> 1, wc = wid & 1;
  const int l15 = lane & 15, kq = lane >> 4;

  // staging source mapping: element e = wid*512 + lane*8 -> (row e>>5, col e&31)
  const int e0 = wid * 512 + lane * 8;
  const int r0 = e0 >> 5, c0 = e0 & 31;
  const size_t aoff0 = (size_t)(bm0 + r0) * lda + c0;
  const size_t aoff1 = (size_t)(bm0 + r0 + 64) * lda + c0;
  const size_t boff0 = (size_t)(bn0 + r0) * ldb + c0;
  const size_t boff1 = (size_t)(bn0 + r0 + 64) * ldb + c0;
  unsigned char* ldsA = lds + wid * 1024;         // wave-uniform base
  unsigned char* ldsB = lds + 8192 + wid * 1024;

  f32x4 acc[4][4] = {};
  const int nkt = K >> 5;
  for (int kt = 0; kt < nkt; ++kt) {
    const int kc = kt << 5;
    gl_lds16(A + aoff0 + kc, ldsA);
    gl_lds16(A + aoff1 + kc, ldsA + 4096);
    gl_lds16(B + boff0 + kc, ldsB);
    gl_lds16(B + boff1 + kc, ldsB + 4096);
    __syncthreads();   // compiler drains vmcnt before s_barrier

    bf16x8 af[4], bg[4];
#pragma unroll
    for (int mi = 0; mi < 4; ++mi)
      af[mi] = *(const bf16x8*)(lds + ((wr * 64 + mi * 16 + l15) * 64 + kq * 16));
#pragma unroll
    for (int ni = 0; ni < 4; ++ni)
      bg[ni] = *(const bf16x8*)(lds + 8192 + ((wc * 64 + ni * 16 + l15) * 64 + kq * 16));
#pragma unroll
    for (int mi = 0; mi < 4; ++mi)
#pragma unroll
      for (int ni = 0; ni < 4; ++ni)
        acc[mi][ni] = __builtin_amdgcn_mfma_f32_16x16x32_bf16(af[mi], bg[ni], acc[mi][ni], 0, 0, 0);
    __syncthreads();
  }

  // epilogue: C/D layout col = lane&15, row = (lane>>4)*4 + reg  [verified m89/m91]
#pragma unroll
  for (int mi = 0; mi < 4; ++mi) {
#pragma unroll
    for (int ni = 0; ni < 4; ++ni) {
#pragma unroll
      for (int r = 0; r < 4; ++r) {
        const int row = bm0 + wr * 64 + mi * 16 + kq * 4 + r;
        const int col = bn0 + wc * 64 + ni * 16 + l15;
        const float v = acc[mi][ni][r];
        if constexpr (MODE == 2) {
          ((float*)Cv)[(size_t)blockIdx.z * cstride + (size_t)row * ldc + col] = v;
        } else {  // MODE 3: fused QKV
          unsigned short* q = (unsigned short*)Cv;
          if (col < 1024) {
            q[(size_t)row * 1024 + col] = f2bf(v);
          } else if (col < 2048) {
            q[16777216u + (size_t)row * 1024 + (col - 1024)] = f2bf(v);
          } else {
            const int b = row >> 11, s = row & 2047;
            q[33554432u + ((size_t)(b * 1024 + (col - 2048))) * 2048 + s] = f2bf(v);
          }
        }
      }
    }
  }
}

// ---------- row softmax over 2048 fp32 scores; writes bf16 P in-place (ld 4096) ----------
// grid: (2048 rows, G batches); scores batch stride 4194304 floats
__global__ __launch_bounds__(256) void softmax_rows(float* __restrict__ scores) {
  float* base = scores + (size_t)blockIdx.y * 4194304 + (size_t)blockIdx.x * 2048;
  const int tid = threadIdx.x;
  const int wid = tid >> 6, lane = tid & 63;

  float v[8];
  float m = -1e30f;
#pragma unroll
  for (int i = 0; i < 8; ++i) {
    v[i] = base[tid + i * 256] * 0.03125f;  // 1/sqrt(1024)
    m = fmaxf(m, v[i]);
  }
  for (int off = 32; off; off >>= 1) m = fmaxf(m, __shfl_xor(m, off));
  __shared__ float redm[4], reds[4];
  if (lane == 0) redm[wid] = m;
  __syncthreads();            // all global reads of this row complete before here
  m = fmaxf(fmaxf(redm[0], redm[1]), fmaxf(redm[2], redm[3]));

  float s = 0.f;
#pragma unroll
  for (int i = 0; i < 8; ++i) { v[i] = expf(v[i] - m); s += v[i]; }
  for (int off = 32; off; off >>= 1) s += __shfl_xor(s, off);
  if (lane == 0) reds[wid] = s;
  __syncthreads();
  s = reds[0] + reds[1] + reds[2] + reds[3];
  const float inv = 1.0f / s;

  unsigned short* p = (unsigned short*)base;  // bf16 P, ld 4096, in-place (safe: writes after barrier)
#pragma unroll
  for (int i = 0; i < 8; ++i) p[tid + i * 256] = f2bf(v[i] * inv);
}

// ---------- launch ----------
extern "C" void kernel_launch(void* const* d_in, const int* in_sizes, int n_in,
                              void* d_out, int out_size, void* d_ws, size_t ws_size,
                              hipStream_t stream) {
  const float* x  = (const float*)d_in[0];
  const float* Wq = (const float*)d_in[1];
  const float* Wk = (const float*)d_in[2];
  const float* Wv = (const float*)d_in[3];
  float* out = (float*)d_out;
  char* ws = (char*)d_ws;

  // workspace layout (bytes)
  unsigned short* xb     = (unsigned short*)ws;                  // 33.5 MB
  unsigned short* wt_all = (unsigned short*)(ws + 33554432);     // 6 MB: WqT|WkT|WvT [3072][1024]
  unsigned short* qb     = (unsigned short*)(ws + 39845888);     // 33.5 MB
  unsigned short* kb     = qb + 16777216;                        // 33.5 MB
  unsigned short* vt     = kb + 16777216;                        // 33.5 MB (vT: [b*1024+e][s])
  const size_t off_scores = 140509184;                           // end of vt

  // scores scratch: 16 MiB per batch (2048 x 2048 fp32). Batch G at a time.
  int G; float* scores;
  if (ws_size >= off_scores + 8ull * 16777216) {
    G = 8; scores = (float*)(ws + off_scores);
  } else if (ws_size >= off_scores + 16777216) {
    size_t g = (ws_size - off_scores) / 16777216; G = (int)(g > 8 ? 8 : g);
    scores = (float*)(ws + off_scores);
  } else {
    G = 2; scores = (float*)ws;  // reuse xb region (39.8 MB >= 2 x 16 MiB); xb dead after QKV
  }

  cast_f32_bf16<<<2048, 256, 0, stream>>>(x, xb, 16384 * 1024);
  transpose_cast_w<<<dim3(64, 64), 256, 0, stream>>>(Wq, wt_all);
  transpose_cast_w<<<dim3(64, 64), 256, 0, stream>>>(Wk, wt_all + 1048576);
  transpose_cast_w<<<dim3(64, 64), 256, 0, stream>>>(Wv, wt_all + 2097152);

  // fused QKV projection: M=16384, N=3072, K=1024
  gemm_bt<3><<<dim3(24, 128), 256, 0, stream>>>(xb, 1024, 0, wt_all, 1024, 0,
                                                1024, qb, 0, 0);

  for (int b0 = 0; b0 < 8; b0 += G) {
    const int g = (8 - b0) < G ? (8 - b0) : G;
    const size_t so = (size_t)b0 * 2097152;  // q/k/v/out batch offset (elems)
    // scores = q·k^T (fp32): M=N=2048, K=1024, batched over z
    gemm_bt<2><<<dim3(16, 16, g), 256, 0, stream>>>(
        qb + so, 1024, 2097152, kb + so, 1024, 2097152, 1024,
        scores, 2048, 4194304);
    // softmax rows (applies 1/32 scale), P bf16 in-place at ld 4096
    softmax_rows<<<dim3(2048, g), 256, 0, stream>>>(scores);
    // out = P·v : A=P (lda 4096 ushort), B^T = vT_b [1024][2048], M=2048, N=1024, K=2048
    gemm_bt<2><<<dim3(8, 16, g), 256, 0, stream>>>(
        (const unsigned short*)scores, 4096, 8388608,
        vt + so, 2048, 2097152, 2048,
        out + so, 1024, 2097152);
  }
}